// Round 1
// baseline (558.672 us; speedup 1.0000x reference)
//
#include <hip/hip_runtime.h>
#include <hip/hip_bf16.h>
#include <math.h>

#define CIN   512
#define COUT  512
#define NB    16
#define WD    512
#define HIN   32
#define HUP   66
#define RES   64
#define LRELU 0.2f
#define ACT_GAIN 1.4142135623730951f

typedef __attribute__((ext_vector_type(8))) short short8;
typedef __attribute__((ext_vector_type(4))) float float4v;

// ---------------- styles = w @ A^T / sqrt(512) + bias ----------------
__global__ void styles2_kernel(const float* __restrict__ w,
                               const float* __restrict__ aw,
                               const float* __restrict__ ab,
                               float* __restrict__ styles) {
    int b = blockIdx.x;          // 16
    int cig = blockIdx.y;        // 8
    int lane = threadIdx.x & 63, wv = threadIdx.x >> 6;
    __shared__ float wsh[WD];
    for (int e = threadIdx.x; e < WD; e += 256) wsh[e] = w[b * WD + e];
    __syncthreads();
    for (int r = 0; r < 16; ++r) {
        int ci = cig * 64 + wv * 16 + r;
        const float* arow = aw + (size_t)ci * WD;
        float acc = 0.f;
        for (int k = lane; k < WD; k += 64) acc += arow[k] * wsh[k];
        for (int off = 32; off; off >>= 1) acc += __shfl_down(acc, off, 64);
        if (lane == 0)
            styles[b * CIN + ci] = acc * 0.04419417382415922f + ab[ci];
    }
}

// ---- weights: wsq fp32 + pre-flipped bf16 pack wb[cc][t][ci_hi][cout][ci_lo] ----
__global__ void prep_weights(const float* __restrict__ weight,
                             float* __restrict__ wsq,
                             __hip_bfloat16* __restrict__ wb) {
    int idx = blockIdx.x * 256 + threadIdx.x;   // 262144
    int co = idx & (COUT - 1);
    int ci = idx >> 9;
    const float* wp = weight + ((size_t)co * CIN + ci) * 9;
    int cc = ci >> 5, chi = (ci >> 3) & 3, clo = ci & 7;
    float s = 0.f;
#pragma unroll
    for (int t = 0; t < 9; ++t) {
        float v = wp[t];
        s += v * v;
        int tf = 8 - t;   // flipped tap
        wb[((((size_t)cc * 9 + tf) * 4 + chi) * COUT + co) * 8 + clo] = __float2bfloat16(v);
    }
    wsq[(size_t)co * CIN + ci] = s;
}

// ---------------- dcoef[b,co] = rsqrt( sum_ci wsq[co,ci]*styles^2 + 1e-8 ) ----------------
__global__ void dcoef2_kernel(const float* __restrict__ styles,
                              const float* __restrict__ wsq,
                              float* __restrict__ dcoef) {
    int b = blockIdx.x;          // 16
    int cog = blockIdx.y;        // 8
    int lane = threadIdx.x & 63, wv = threadIdx.x >> 6;
    __shared__ float s2[CIN];
    for (int e = threadIdx.x; e < CIN; e += 256) {
        float s = styles[b * CIN + e];
        s2[e] = s * s;
    }
    __syncthreads();
    for (int r = 0; r < 16; ++r) {
        int co = cog * 64 + wv * 16 + r;
        const float* qrow = wsq + (size_t)co * CIN;
        float acc = 0.f;
        for (int k = lane; k < CIN; k += 64) acc += qrow[k] * s2[k];
        for (int off = 32; off; off >>= 1) acc += __shfl_down(acc, off, 64);
        if (lane == 0) dcoef[b * COUT + co] = rsqrtf(acc + 1e-8f);
    }
}

// ------- fused upsample x2 (upfirdn [1,3,3,1]/8) * styles -> channels-last bf16 -------
// xs2[b][row(66)][col(66)][ci(512)]
__global__ void upmod2_kernel(const float* __restrict__ x,
                              const float* __restrict__ styles,
                              __hip_bfloat16* __restrict__ xs2) {
    __shared__ float xt[128 * 65];
    const int oh = blockIdx.x;        // 0..65
    const int ci0 = blockIdx.y * 128; // 4 groups
    const int b = blockIdx.z;
    int m0, m1; float a0, a1;
    if (oh & 1) { m0 = (oh - 3) >> 1; a0 = 0.125f; m1 = (oh - 1) >> 1; a1 = 0.375f; }
    else        { m0 = (oh >> 1) - 1; a0 = 0.375f; m1 = (oh >> 1);     a1 = 0.125f; }
    for (int e = threadIdx.x; e < 8192; e += 256) {
        int ci = e >> 6, sel = (e >> 5) & 1, iw = e & 31;
        int m = sel ? m1 : m0;
        float v = 0.f;
        if (m >= 0 && m < HIN)
            v = x[((size_t)(b * CIN + ci0 + ci) * HIN + m) * HIN + iw];
        xt[ci * 65 + sel * 32 + iw] = v;
    }
    __syncthreads();
    for (int e = threadIdx.x; e < 66 * 128; e += 256) {
        int ci = e & 127, ow = e >> 7;
        int n0i, n1i; float b0, b1;
        if (ow & 1) { n0i = (ow - 3) >> 1; b0 = 0.125f; n1i = (ow - 1) >> 1; b1 = 0.375f; }
        else        { n0i = (ow >> 1) - 1; b0 = 0.375f; n1i = (ow >> 1);     b1 = 0.125f; }
        bool c0 = (n0i >= 0) & (n0i < HIN);
        bool c1 = (n1i >= 0) & (n1i < HIN);
        float r0 = (c0 ? xt[ci * 65 + n0i] : 0.f) * b0 + (c1 ? xt[ci * 65 + n1i] : 0.f) * b1;
        float r1 = (c0 ? xt[ci * 65 + 32 + n0i] : 0.f) * b0 + (c1 ? xt[ci * 65 + 32 + n1i] : 0.f) * b1;
        float s = styles[b * CIN + ci0 + ci] * 4.0f;
        float val = (a0 * r0 + a1 * r1) * s;
        xs2[(((size_t)b * HUP + oh) * HUP + ow) * CIN + ci0 + ci] = __float2bfloat16(val);
    }
}

// ---------------- implicit-GEMM conv via MFMA bf16 16x16x32 ----------------
// block: 4 waves; tile M=256 px (4 image rows), N=64 cout; K-chunk = 32 ci.
// LDS A: [r(6)][ci_hi(4)][col(66)][ci_lo(8)] bf16 = 25344 B (padded to 25600)
// LDS B: [t(9)][ci_hi(4)][n(64)][ci_lo(8)]  bf16 = 36864 B
// T14 register-staged pipeline: issue cc+1 global loads into VGPRs before
// computing cc; drain + ds_write after the post-compute barrier.
#define LDA_SZ 25600
#define LDB_SZ 36864

__global__ __launch_bounds__(256, 2) void conv_mfma(
        const __hip_bfloat16* __restrict__ xs2,
        const __hip_bfloat16* __restrict__ wb,
        const float* __restrict__ dcoef,
        const float* __restrict__ bias,
        const float* __restrict__ noise,
        const float* __restrict__ nstr,
        float* __restrict__ out)
{
    __shared__ __align__(16) char smem[LDA_SZ + LDB_SZ];
    const int tid = threadIdx.x;
    const int lane = tid & 63;
    const int wid = tid >> 6;
    const int li = lane & 15;
    const int q = lane >> 4;
    const int mt = blockIdx.x;        // 0..15 -> rows y0..y0+3
    const int n0 = blockIdx.y * 64;   // cout base
    const int b  = blockIdx.z;
    const int y0 = mt * 4;

    // ---- precompute staging descriptors ----
    long a_goff[7];   // element offsets into xs2 (without ci0)
    int  a_lds[7];
#pragma unroll
    for (int k = 0; k < 7; ++k) {
        int n = wid + k * 4;
        if (n < 25) {
            int s = n * 64 + lane;          // 16B slot id
            if (s > 1583) s = 1583;         // clamp tail into pad region
            int r = s / 264;
            int rem = s - r * 264;
            int chi = rem / 66;
            int col = rem - chi * 66;
            a_goff[k] = ((long)(b * HUP + y0 + r) * HUP + col) * CIN + chi * 8;
            a_lds[k] = n * 1024;
        } else { a_goff[k] = 0; a_lds[k] = -1; }
    }
    long b_goff[9];   // element offsets into wb (without cc term)
#pragma unroll
    for (int k = 0; k < 9; ++k) {
        int sl = wid + k * 4;               // 0..35: t = sl>>2, chi = sl&3
        b_goff[k] = ((long)sl * COUT + n0) * 8 + (long)lane * 8;
    }

    float4v acc[4][4];
#pragma unroll
    for (int i = 0; i < 4; ++i)
#pragma unroll
        for (int j = 0; j < 4; ++j) acc[i][j] = (float4v)0.f;

    const char* xg = (const char*)xs2;
    const char* wg = (const char*)wb;

    // staging registers (statically indexed everywhere — full unroll)
    float4v rA[7];
    float4v rB[9];

#define ISSUE_LOADS(CC) do {                                                  \
        long ccl_ = (long)(CC);                                               \
        _Pragma("unroll")                                                     \
        for (int k = 0; k < 9; ++k)                                           \
            rB[k] = *(const float4v*)(wg + (ccl_ * 147456 + b_goff[k]) * 2);  \
        _Pragma("unroll")                                                     \
        for (int k = 0; k < 7; ++k)                                           \
            if (a_lds[k] >= 0)                                                \
                rA[k] = *(const float4v*)(xg + (a_goff[k] + ccl_ * 32) * 2);  \
    } while (0)

#define WRITE_LDS() do {                                                      \
        _Pragma("unroll")                                                     \
        for (int k = 0; k < 9; ++k)                                           \
            *(float4v*)(smem + LDA_SZ + (wid + k * 4) * 1024 + lane * 16)     \
                = rB[k];                                                      \
        _Pragma("unroll")                                                     \
        for (int k = 0; k < 7; ++k)                                           \
            if (a_lds[k] >= 0)                                                \
                *(float4v*)(smem + a_lds[k] + lane * 16) = rA[k];             \
    } while (0)

    // prologue: stage cc=0
    ISSUE_LOADS(0);
    WRITE_LDS();
    __syncthreads();

    for (int cc = 0; cc < 16; ++cc) {
        // issue next tile's global loads early — latency hides under MFMA
        if (cc < 15) ISSUE_LOADS(cc + 1);
        __builtin_amdgcn_sched_barrier(0);   // pin loads above the MFMA region

        __builtin_amdgcn_s_setprio(1);
#pragma unroll
        for (int t = 0; t < 9; ++t) {
            const int kh = t / 3, kw = t - kh * 3;
            short8 bf[4];
#pragma unroll
            for (int j = 0; j < 4; ++j)
                bf[j] = *(const short8*)(smem + LDA_SZ +
                        (((t * 4 + q) * 64) + j * 16 + li) * 16);
#pragma unroll
            for (int i = 0; i < 4; ++i) {
                short8 af = *(const short8*)(smem +
                        ((((wid + kh) * 4 + q) * 66) + (i * 16 + li + kw)) * 16);
#pragma unroll
                for (int j = 0; j < 4; ++j)
                    acc[i][j] = __builtin_amdgcn_mfma_f32_16x16x32_bf16(
                        af, bf[j], acc[i][j], 0, 0, 0);
            }
        }
        __builtin_amdgcn_s_setprio(0);

        __syncthreads();                     // all waves done reading lds[cc]
        if (cc < 15) {
            WRITE_LDS();                     // vmcnt drain happens here (cheap now)
            __syncthreads();                 // lds[cc+1] ready
        }
    }

#undef ISSUE_LOADS
#undef WRITE_LDS

    // ---- epilogue: *dcoef + noise + bias -> lrelu*gain ----
    const float ns = nstr[0];
    const int row = y0 + wid;
#pragma unroll
    for (int j = 0; j < 4; ++j) {
        int cout = n0 + j * 16 + li;
        float dc = dcoef[b * COUT + cout];
        float bs = bias[cout];
        float* op = out + ((size_t)(b * COUT + cout) * RES + row) * RES;
#pragma unroll
        for (int i = 0; i < 4; ++i) {
            int colb = i * 16 + q * 4;
            float4v nz = *(const float4v*)(noise + row * RES + colb);
            float4v a = acc[i][j];
            float4v r;
            r.x = a.x * dc + nz.x * ns + bs;
            r.y = a.y * dc + nz.y * ns + bs;
            r.z = a.z * dc + nz.z * ns + bs;
            r.w = a.w * dc + nz.w * ns + bs;
            r.x = (r.x > 0.f ? r.x : LRELU * r.x) * ACT_GAIN;
            r.y = (r.y > 0.f ? r.y : LRELU * r.y) * ACT_GAIN;
            r.z = (r.z > 0.f ? r.z : LRELU * r.z) * ACT_GAIN;
            r.w = (r.w > 0.f ? r.w : LRELU * r.w) * ACT_GAIN;
            *(float4v*)(op + colb) = r;
        }
    }
}

extern "C" void kernel_launch(void* const* d_in, const int* in_sizes, int n_in,
                              void* d_out, int out_size, void* d_ws, size_t ws_size,
                              hipStream_t stream) {
    (void)in_sizes; (void)n_in; (void)out_size; (void)ws_size;
    const float* x     = (const float*)d_in[0];
    const float* w     = (const float*)d_in[1];
    const float* aw    = (const float*)d_in[2];
    const float* ab    = (const float*)d_in[3];
    const float* wt    = (const float*)d_in[4];
    const float* bias  = (const float*)d_in[5];
    const float* noise = (const float*)d_in[6];
    const float* nstr  = (const float*)d_in[7];
    float* out = (float*)d_out;

    char* ws = (char*)d_ws;
    float* styles = (float*)ws;                                   // 32 KB
    float* dcoef  = (float*)(ws + 32768);                         // 32 KB
    float* wsq    = (float*)(ws + 65536);                         // 1 MB
    __hip_bfloat16* wb  = (__hip_bfloat16*)(ws + 65536 + 1048576);          // 4.72 MB
    __hip_bfloat16* xs2 = (__hip_bfloat16*)(ws + 65536 + 1048576 + 4718592); // 71.4 MB

    styles2_kernel<<<dim3(NB, 8), dim3(256), 0, stream>>>(w, aw, ab, styles);
    prep_weights<<<dim3(1024), dim3(256), 0, stream>>>(wt, wsq, wb);
    dcoef2_kernel<<<dim3(NB, 8), dim3(256), 0, stream>>>(styles, wsq, dcoef);
    upmod2_kernel<<<dim3(HUP, 4, NB), dim3(256), 0, stream>>>(x, styles, xs2);
    conv_mfma<<<dim3(16, 8, NB), dim3(256), 0, stream>>>(
        xs2, wb, dcoef, bias, noise, nstr, out);
}

// Round 2
// 523.866 us; speedup vs baseline: 1.0664x; 1.0664x over previous
//
#include <hip/hip_runtime.h>
#include <hip/hip_bf16.h>
#include <math.h>

#define CIN   512
#define COUT  512
#define NB    16
#define WD    512
#define HIN   32
#define HUP   66
#define RES   64
#define LRELU 0.2f
#define ACT_GAIN 1.4142135623730951f

typedef __attribute__((ext_vector_type(8))) short short8;
typedef __attribute__((ext_vector_type(4))) float float4v;

// ---------------- styles = w @ A^T / sqrt(512) + bias ----------------
__global__ void styles2_kernel(const float* __restrict__ w,
                               const float* __restrict__ aw,
                               const float* __restrict__ ab,
                               float* __restrict__ styles) {
    int b = blockIdx.x;          // 16
    int cig = blockIdx.y;        // 8
    int lane = threadIdx.x & 63, wv = threadIdx.x >> 6;
    __shared__ float wsh[WD];
    for (int e = threadIdx.x; e < WD; e += 256) wsh[e] = w[b * WD + e];
    __syncthreads();
    for (int r = 0; r < 16; ++r) {
        int ci = cig * 64 + wv * 16 + r;
        const float* arow = aw + (size_t)ci * WD;
        float acc = 0.f;
        for (int k = lane; k < WD; k += 64) acc += arow[k] * wsh[k];
        for (int off = 32; off; off >>= 1) acc += __shfl_down(acc, off, 64);
        if (lane == 0)
            styles[b * CIN + ci] = acc * 0.04419417382415922f + ab[ci];
    }
}

// ---- weights: wsq fp32 + pre-flipped bf16 pack wb[cc][t][ci_hi][cout][ci_lo] ----
__global__ void prep_weights(const float* __restrict__ weight,
                             float* __restrict__ wsq,
                             __hip_bfloat16* __restrict__ wb) {
    int idx = blockIdx.x * 256 + threadIdx.x;   // 262144
    int co = idx & (COUT - 1);
    int ci = idx >> 9;
    const float* wp = weight + ((size_t)co * CIN + ci) * 9;
    int cc = ci >> 5, chi = (ci >> 3) & 3, clo = ci & 7;
    float s = 0.f;
#pragma unroll
    for (int t = 0; t < 9; ++t) {
        float v = wp[t];
        s += v * v;
        int tf = 8 - t;   // flipped tap
        wb[((((size_t)cc * 9 + tf) * 4 + chi) * COUT + co) * 8 + clo] = __float2bfloat16(v);
    }
    wsq[(size_t)co * CIN + ci] = s;
}

// ---------------- dcoef[b,co] = rsqrt( sum_ci wsq[co,ci]*styles^2 + 1e-8 ) ----------------
__global__ void dcoef2_kernel(const float* __restrict__ styles,
                              const float* __restrict__ wsq,
                              float* __restrict__ dcoef) {
    int b = blockIdx.x;          // 16
    int cog = blockIdx.y;        // 8
    int lane = threadIdx.x & 63, wv = threadIdx.x >> 6;
    __shared__ float s2[CIN];
    for (int e = threadIdx.x; e < CIN; e += 256) {
        float s = styles[b * CIN + e];
        s2[e] = s * s;
    }
    __syncthreads();
    for (int r = 0; r < 16; ++r) {
        int co = cog * 64 + wv * 16 + r;
        const float* qrow = wsq + (size_t)co * CIN;
        float acc = 0.f;
        for (int k = lane; k < CIN; k += 64) acc += qrow[k] * s2[k];
        for (int off = 32; off; off >>= 1) acc += __shfl_down(acc, off, 64);
        if (lane == 0) dcoef[b * COUT + co] = rsqrtf(acc + 1e-8f);
    }
}

// ------- fused upsample x2 (upfirdn [1,3,3,1]/8) * styles -> channels-last bf16 -------
// xs2[b][row(66)][col(66)][ci(512)]
// Vectorized: float4 x loads, short8 (16B) stores, styles cached in LDS.
__global__ void upmod2_kernel(const float* __restrict__ x,
                              const float* __restrict__ styles,
                              __hip_bfloat16* __restrict__ xs2) {
    __shared__ float xt[128 * 68];   // [ci(128)][sel(2)*32 + iw], stride 68 (16B aligned)
    __shared__ float ssh[128];
    const int oh = blockIdx.x;        // 0..65
    const int ci0 = blockIdx.y * 128; // 4 groups
    const int b = blockIdx.z;
    int m0, m1; float a0, a1;
    if (oh & 1) { m0 = (oh - 3) >> 1; a0 = 0.125f; m1 = (oh - 1) >> 1; a1 = 0.375f; }
    else        { m0 = (oh >> 1) - 1; a0 = 0.375f; m1 = (oh >> 1);     a1 = 0.125f; }
    if (threadIdx.x < 128) ssh[threadIdx.x] = styles[b * CIN + ci0 + threadIdx.x] * 4.0f;
    for (int e = threadIdx.x; e < 2048; e += 256) {
        int ci = e >> 4, sel = (e >> 3) & 1, iw4 = e & 7;
        int m = sel ? m1 : m0;
        float4v v = (float4v)0.f;
        if (m >= 0 && m < HIN)
            v = *(const float4v*)(x + ((size_t)(b * CIN + ci0 + ci) * HIN + m) * HIN + iw4 * 4);
        *(float4v*)(&xt[ci * 68 + sel * 32 + iw4 * 4]) = v;
    }
    __syncthreads();
    for (int e = threadIdx.x; e < 1056; e += 256) {   // 16 cig * 66 ow
        int cig = e / 66;
        int ow = e - cig * 66;
        int n0i, n1i; float b0, b1;
        if (ow & 1) { n0i = (ow - 3) >> 1; b0 = 0.125f; n1i = (ow - 1) >> 1; b1 = 0.375f; }
        else        { n0i = (ow >> 1) - 1; b0 = 0.375f; n1i = (ow >> 1);     b1 = 0.125f; }
        bool c0 = (n0i >= 0) & (n0i < HIN);
        bool c1 = (n1i >= 0) & (n1i < HIN);
        short8 sv;
#pragma unroll
        for (int u = 0; u < 8; ++u) {
            int ci = cig * 8 + u;
            const float* base = &xt[ci * 68];
            float r0 = (c0 ? base[n0i] : 0.f) * b0 + (c1 ? base[n1i] : 0.f) * b1;
            float r1 = (c0 ? base[32 + n0i] : 0.f) * b0 + (c1 ? base[32 + n1i] : 0.f) * b1;
            float val = (a0 * r0 + a1 * r1) * ssh[ci];
            __hip_bfloat16 h = __float2bfloat16(val);
            sv[u] = *reinterpret_cast<const short*>(&h);
        }
        *reinterpret_cast<short8*>(
            xs2 + (((size_t)b * HUP + oh) * HUP + ow) * CIN + ci0 + cig * 8) = sv;
    }
}

// ---------------- implicit-GEMM conv via MFMA bf16 16x16x32 ----------------
// block: 4 waves tiling M; block tile M=512 px (8 output rows), N=64 cout.
// wave tile M=128 (acc[8][4]) -> LDS bytes/FLOP = (128+64)/(128*64) = 1/42.7.
// LDS A: [r(10)][chi(4)][col(66)][ci_lo(8)] bf16 = 42240 B -> 42 x 1KB slices (43008)
// LDS B: [t(9)][chi(4, stride 1056B)][n(64)][ci_lo(8)] = 38016 B  (chi pad kills
//        the 4-way bank conflict: 1056/4 mod 32 = 8-bank shift per chi group)
// Total 81024 B dynamic LDS -> 2 blocks/CU (162048 <= 163840).
#define LDA_SZ 43008
#define LDB_SZ 38016
#define LDS_TOT (LDA_SZ + LDB_SZ)

__global__ __launch_bounds__(256, 2) void conv_mfma(
        const __hip_bfloat16* __restrict__ xs2,
        const __hip_bfloat16* __restrict__ wb,
        const float* __restrict__ dcoef,
        const float* __restrict__ bias,
        const float* __restrict__ noise,
        const float* __restrict__ nstr,
        float* __restrict__ out)
{
    extern __shared__ __align__(16) char smem[];
    const int tid = threadIdx.x;
    const int lane = tid & 63;
    const int wid = tid >> 6;
    const int li = lane & 15;
    const int q = lane >> 4;
    const int mb = blockIdx.x;        // 0..7 -> output rows y0..y0+7
    const int n0 = blockIdx.y * 64;   // cout base
    const int b  = blockIdx.z;
    const int y0 = mb * 8;

    // ---- staging descriptors (element offsets fit in int) ----
    int a_goff[11];
    int a_lds[11];
#pragma unroll
    for (int k = 0; k < 11; ++k) {
        int n = wid + k * 4;
        if (n < 42) {
            int s = n * 64 + lane;          // 16B slot id, valid 0..2639
            if (s > 2639) s = 2639;         // clamp tail into duplicate region
            int r = s / 264;
            int rem = s - r * 264;
            int chi = rem / 66;
            int col = rem - chi * 66;
            a_goff[k] = ((b * HUP + y0 + r) * HUP + col) * CIN + chi * 8;
            a_lds[k] = n * 1024;
        } else { a_goff[k] = 0; a_lds[k] = -1; }
    }
    int b_goff[9], b_lds[9];
#pragma unroll
    for (int k = 0; k < 9; ++k) {
        int sl = wid + k * 4;               // 0..35: t = sl>>2, chi = sl&3
        b_goff[k] = (sl * COUT + n0 + lane) * 8;
        b_lds[k] = LDA_SZ + (sl >> 2) * 4224 + (sl & 3) * 1056;
    }

    float4v acc[8][4];
#pragma unroll
    for (int i = 0; i < 8; ++i)
#pragma unroll
        for (int j = 0; j < 4; ++j) acc[i][j] = (float4v)0.f;

    const char* xg = (const char*)xs2;
    const char* wg = (const char*)wb;

    for (int cc = 0; cc < 16; ++cc) {
        // B: 36 slices, 9 per wave
#pragma unroll
        for (int k = 0; k < 9; ++k) {
            long ge = (long)(b_goff[k] + cc * 147456);
            __builtin_amdgcn_global_load_lds(
                (const __attribute__((address_space(1))) char*)(wg + ge * 2),
                (__attribute__((address_space(3))) char*)(smem + b_lds[k]),
                16, 0, 0);
        }
        // A: 42 slices, 10-11 per wave
#pragma unroll
        for (int k = 0; k < 11; ++k) {
            if (a_lds[k] >= 0) {
                long ge = (long)(a_goff[k] + cc * 32);
                __builtin_amdgcn_global_load_lds(
                    (const __attribute__((address_space(1))) char*)(xg + ge * 2),
                    (__attribute__((address_space(3))) char*)(smem + a_lds[k]),
                    16, 0, 0);
            }
        }
        __syncthreads();

#pragma unroll
        for (int t = 0; t < 9; ++t) {
            const int kh = t / 3, kw = t - kh * 3;
            short8 bf[4];
#pragma unroll
            for (int j = 0; j < 4; ++j)
                bf[j] = *(const short8*)(smem + LDA_SZ + t * 4224 + q * 1056 +
                                         (j * 16 + li) * 16);
#pragma unroll
            for (int i = 0; i < 8; ++i) {
                int rl = wid * 2 + (i >> 2) + kh;    // 0..9
                short8 af = *(const short8*)(smem +
                        ((rl * 4 + q) * 66 + ((i & 3) * 16 + li + kw)) * 16);
#pragma unroll
                for (int j = 0; j < 4; ++j)
                    acc[i][j] = __builtin_amdgcn_mfma_f32_16x16x32_bf16(
                        af, bf[j], acc[i][j], 0, 0, 0);
            }
        }
        __syncthreads();
    }

    // ---- epilogue: *dcoef + noise + bias -> lrelu*gain ----
    const float ns = nstr[0];
#pragma unroll
    for (int j = 0; j < 4; ++j) {
        int cout = n0 + j * 16 + li;
        float dc = dcoef[b * COUT + cout];
        float bs = bias[cout];
#pragma unroll
        for (int i = 0; i < 8; ++i) {
            int row = y0 + wid * 2 + (i >> 2);
            int colb = (i & 3) * 16 + q * 4;
            float* op = out + ((size_t)(b * COUT + cout) * RES + row) * RES + colb;
            float4v nz = *(const float4v*)(noise + row * RES + colb);
            float4v a = acc[i][j];
            float4v r;
            r.x = a.x * dc + nz.x * ns + bs;
            r.y = a.y * dc + nz.y * ns + bs;
            r.z = a.z * dc + nz.z * ns + bs;
            r.w = a.w * dc + nz.w * ns + bs;
            r.x = (r.x > 0.f ? r.x : LRELU * r.x) * ACT_GAIN;
            r.y = (r.y > 0.f ? r.y : LRELU * r.y) * ACT_GAIN;
            r.z = (r.z > 0.f ? r.z : LRELU * r.z) * ACT_GAIN;
            r.w = (r.w > 0.f ? r.w : LRELU * r.w) * ACT_GAIN;
            *(float4v*)op = r;
        }
    }
}

extern "C" void kernel_launch(void* const* d_in, const int* in_sizes, int n_in,
                              void* d_out, int out_size, void* d_ws, size_t ws_size,
                              hipStream_t stream) {
    (void)in_sizes; (void)n_in; (void)out_size; (void)ws_size;
    const float* x     = (const float*)d_in[0];
    const float* w     = (const float*)d_in[1];
    const float* aw    = (const float*)d_in[2];
    const float* ab    = (const float*)d_in[3];
    const float* wt    = (const float*)d_in[4];
    const float* bias  = (const float*)d_in[5];
    const float* noise = (const float*)d_in[6];
    const float* nstr  = (const float*)d_in[7];
    float* out = (float*)d_out;

    static bool init = false;
    if (!init) {
        hipFuncSetAttribute(reinterpret_cast<const void*>(conv_mfma),
                            hipFuncAttributeMaxDynamicSharedMemorySize, LDS_TOT);
        init = true;
    }

    char* ws = (char*)d_ws;
    float* styles = (float*)ws;                                   // 32 KB
    float* dcoef  = (float*)(ws + 32768);                         // 32 KB
    float* wsq    = (float*)(ws + 65536);                         // 1 MB
    __hip_bfloat16* wb  = (__hip_bfloat16*)(ws + 65536 + 1048576);          // 4.72 MB
    __hip_bfloat16* xs2 = (__hip_bfloat16*)(ws + 65536 + 1048576 + 4718592); // 71.4 MB

    styles2_kernel<<<dim3(NB, 8), dim3(256), 0, stream>>>(w, aw, ab, styles);
    prep_weights<<<dim3(1024), dim3(256), 0, stream>>>(wt, wsq, wb);
    dcoef2_kernel<<<dim3(NB, 8), dim3(256), 0, stream>>>(styles, wsq, dcoef);
    upmod2_kernel<<<dim3(HUP, 4, NB), dim3(256), 0, stream>>>(x, styles, xs2);
    conv_mfma<<<dim3(8, 8, NB), dim3(256), LDS_TOT, stream>>>(
        xs2, wb, dcoef, bias, noise, nstr, out);
}

// Round 3
// 492.646 us; speedup vs baseline: 1.1340x; 1.0634x over previous
//
#include <hip/hip_runtime.h>
#include <hip/hip_bf16.h>
#include <math.h>

#define CIN   512
#define COUT  512
#define NB    16
#define WD    512
#define HIN   32
#define HUP   66
#define RES   64
#define LRELU 0.2f
#define ACT_GAIN 1.4142135623730951f

typedef __attribute__((ext_vector_type(8))) short short8;
typedef __attribute__((ext_vector_type(4))) float float4v;

// ---------------- styles = w @ A^T / sqrt(512) + bias ----------------
__global__ void styles2_kernel(const float* __restrict__ w,
                               const float* __restrict__ aw,
                               const float* __restrict__ ab,
                               float* __restrict__ styles) {
    int b = blockIdx.x;          // 16
    int cig = blockIdx.y;        // 8
    int lane = threadIdx.x & 63, wv = threadIdx.x >> 6;
    __shared__ float wsh[WD];
    for (int e = threadIdx.x; e < WD; e += 256) wsh[e] = w[b * WD + e];
    __syncthreads();
    for (int r = 0; r < 16; ++r) {
        int ci = cig * 64 + wv * 16 + r;
        const float* arow = aw + (size_t)ci * WD;
        float acc = 0.f;
        for (int k = lane; k < WD; k += 64) acc += arow[k] * wsh[k];
        for (int off = 32; off; off >>= 1) acc += __shfl_down(acc, off, 64);
        if (lane == 0)
            styles[b * CIN + ci] = acc * 0.04419417382415922f + ab[ci];
    }
}

// ---- weights: wsq fp32 + pre-flipped bf16 pack wb[cc][t][ci_hi][cout][ci_lo] ----
__global__ void prep_weights(const float* __restrict__ weight,
                             float* __restrict__ wsq,
                             __hip_bfloat16* __restrict__ wb) {
    int idx = blockIdx.x * 256 + threadIdx.x;   // 262144
    int co = idx & (COUT - 1);
    int ci = idx >> 9;
    const float* wp = weight + ((size_t)co * CIN + ci) * 9;
    int cc = ci >> 5, chi = (ci >> 3) & 3, clo = ci & 7;
    float s = 0.f;
#pragma unroll
    for (int t = 0; t < 9; ++t) {
        float v = wp[t];
        s += v * v;
        int tf = 8 - t;   // flipped tap
        wb[((((size_t)cc * 9 + tf) * 4 + chi) * COUT + co) * 8 + clo] = __float2bfloat16(v);
    }
    wsq[(size_t)co * CIN + ci] = s;
}

// ---------------- dcoef[b,co] = rsqrt( sum_ci wsq[co,ci]*styles^2 + 1e-8 ) ----------------
__global__ void dcoef2_kernel(const float* __restrict__ styles,
                              const float* __restrict__ wsq,
                              float* __restrict__ dcoef) {
    int b = blockIdx.x;          // 16
    int cog = blockIdx.y;        // 8
    int lane = threadIdx.x & 63, wv = threadIdx.x >> 6;
    __shared__ float s2[CIN];
    for (int e = threadIdx.x; e < CIN; e += 256) {
        float s = styles[b * CIN + e];
        s2[e] = s * s;
    }
    __syncthreads();
    for (int r = 0; r < 16; ++r) {
        int co = cog * 64 + wv * 16 + r;
        const float* qrow = wsq + (size_t)co * CIN;
        float acc = 0.f;
        for (int k = lane; k < CIN; k += 64) acc += qrow[k] * s2[k];
        for (int off = 32; off; off >>= 1) acc += __shfl_down(acc, off, 64);
        if (lane == 0) dcoef[b * COUT + co] = rsqrtf(acc + 1e-8f);
    }
}

// ------- fused upsample x2 (upfirdn [1,3,3,1]/8) * styles -> channels-last bf16 -------
// xs2[b][row(66)][col(66)][ci(512)]
__global__ void upmod2_kernel(const float* __restrict__ x,
                              const float* __restrict__ styles,
                              __hip_bfloat16* __restrict__ xs2) {
    __shared__ float xt[128 * 68];
    __shared__ float ssh[128];
    const int oh = blockIdx.x;        // 0..65
    const int ci0 = blockIdx.y * 128; // 4 groups
    const int b = blockIdx.z;
    int m0, m1; float a0, a1;
    if (oh & 1) { m0 = (oh - 3) >> 1; a0 = 0.125f; m1 = (oh - 1) >> 1; a1 = 0.375f; }
    else        { m0 = (oh >> 1) - 1; a0 = 0.375f; m1 = (oh >> 1);     a1 = 0.125f; }
    if (threadIdx.x < 128) ssh[threadIdx.x] = styles[b * CIN + ci0 + threadIdx.x] * 4.0f;
    for (int e = threadIdx.x; e < 2048; e += 256) {
        int ci = e >> 4, sel = (e >> 3) & 1, iw4 = e & 7;
        int m = sel ? m1 : m0;
        float4v v = (float4v)0.f;
        if (m >= 0 && m < HIN)
            v = *(const float4v*)(x + ((size_t)(b * CIN + ci0 + ci) * HIN + m) * HIN + iw4 * 4);
        *(float4v*)(&xt[ci * 68 + sel * 32 + iw4 * 4]) = v;
    }
    __syncthreads();
    for (int e = threadIdx.x; e < 1056; e += 256) {   // 16 cig * 66 ow
        int cig = e / 66;
        int ow = e - cig * 66;
        int n0i, n1i; float b0, b1;
        if (ow & 1) { n0i = (ow - 3) >> 1; b0 = 0.125f; n1i = (ow - 1) >> 1; b1 = 0.375f; }
        else        { n0i = (ow >> 1) - 1; b0 = 0.375f; n1i = (ow >> 1);     b1 = 0.125f; }
        bool c0 = (n0i >= 0) & (n0i < HIN);
        bool c1 = (n1i >= 0) & (n1i < HIN);
        short8 sv;
#pragma unroll
        for (int u = 0; u < 8; ++u) {
            int ci = cig * 8 + u;
            const float* base = &xt[ci * 68];
            float r0 = (c0 ? base[n0i] : 0.f) * b0 + (c1 ? base[n1i] : 0.f) * b1;
            float r1 = (c0 ? base[32 + n0i] : 0.f) * b0 + (c1 ? base[32 + n1i] : 0.f) * b1;
            float val = (a0 * r0 + a1 * r1) * ssh[ci];
            __hip_bfloat16 h = __float2bfloat16(val);
            sv[u] = *reinterpret_cast<const short*>(&h);
        }
        *reinterpret_cast<short8*>(
            xs2 + (((size_t)b * HUP + oh) * HUP + ow) * CIN + ci0 + cig * 8) = sv;
    }
}

// ---------------- implicit-GEMM conv via MFMA bf16 16x16x32 ----------------
// 8 waves (512 thr); block tile M=512 px (8 rows, 1 row/wave), N=64 cout.
// Double-buffered LDS, T3/T4 schedule: issue next-cc global_load_lds FIRST,
// compute 9 taps from current buffer, then vmcnt(0) (latency already hidden
// under ~1400 cyc of MFMA) + ONE s_barrier per cc. cc-loop unrolled x2 so all
// LDS offsets are compile-time constants (provably disjoint buffers).
// Buffer: A [r(10)][chi(4)][col(66)][ci_lo(8)] = 42240 B (padded to 43008, 42
//         1KB slices, tail clamped); B [t(9)][chi(4)][n(64)][ci_lo(8)] = 36864 B
//         (256B-aligned quarters -> conflict-free, the R0 layout).
#define ABUF 43008
#define BBUF 36864
#define BUFSZ (ABUF + BBUF)          // 79872
#define LDS_TOT (2 * BUFSZ)          // 159744 <= 163840

__global__ __launch_bounds__(512, 1) void conv_mfma(
        const __hip_bfloat16* __restrict__ xs2,
        const __hip_bfloat16* __restrict__ wb,
        const float* __restrict__ dcoef,
        const float* __restrict__ bias,
        const float* __restrict__ noise,
        const float* __restrict__ nstr,
        float* __restrict__ out)
{
    extern __shared__ __align__(16) char smem[];
    const int tid = threadIdx.x;
    const int lane = tid & 63;
    const int wid = tid >> 6;        // 0..7
    const int li = lane & 15;
    const int q = lane >> 4;
    const int mb = blockIdx.x;       // 0..7 -> rows y0..y0+7
    const int n0 = blockIdx.y * 64;  // cout base
    const int b  = blockIdx.z;
    const int y0 = mb * 8;

    // ---- staging descriptors ----
    // A: 42 slices of 1KB; wave w takes n = w + k*8 (k=0..5, n<42)
    int a_goff[6];
#pragma unroll
    for (int k = 0; k < 6; ++k) {
        int n = wid + k * 8;
        int s = n * 64 + lane;          // 16B slot id, valid 0..2639
        if (s > 2639) s = 2639;         // clamp tail into pad region
        int r = s / 264;
        int rem = s - r * 264;
        int chi = rem / 66;
        int col = rem - chi * 66;
        a_goff[k] = ((b * HUP + y0 + r) * HUP + col) * CIN + chi * 8;
    }
    // B: 36 slices of 1KB; wave w takes sl = w + k*8 (k=0..4, sl<36)
    int b_goff[5];
#pragma unroll
    for (int k = 0; k < 5; ++k) {
        int sl = wid + k * 8;           // t = sl>>2, chi = sl&3
        b_goff[k] = (sl * COUT + n0 + lane) * 8;
    }

    float4v acc[4][4];
#pragma unroll
    for (int i = 0; i < 4; ++i)
#pragma unroll
        for (int j = 0; j < 4; ++j) acc[i][j] = (float4v)0.f;

    const char* xg = (const char*)xs2;
    const char* wg = (const char*)wb;

#define STAGE(CC, BUFB) do {                                                  \
        _Pragma("unroll")                                                     \
        for (int k = 0; k < 5; ++k) {                                         \
            int sl = wid + k * 8;                                             \
            if (sl < 36) {                                                    \
                long ge = (long)(b_goff[k] + (CC) * 147456);                  \
                __builtin_amdgcn_global_load_lds(                             \
                    (const __attribute__((address_space(1))) char*)(wg + ge * 2), \
                    (__attribute__((address_space(3))) char*)(smem + (BUFB) + ABUF + sl * 1024), \
                    16, 0, 0);                                                \
            }                                                                 \
        }                                                                     \
        _Pragma("unroll")                                                     \
        for (int k = 0; k < 6; ++k) {                                         \
            int n = wid + k * 8;                                              \
            if (n < 42) {                                                     \
                long ge = (long)(a_goff[k] + (CC) * 32);                      \
                __builtin_amdgcn_global_load_lds(                             \
                    (const __attribute__((address_space(1))) char*)(xg + ge * 2), \
                    (__attribute__((address_space(3))) char*)(smem + (BUFB) + n * 1024), \
                    16, 0, 0);                                                \
            }                                                                 \
        }                                                                     \
    } while (0)

#define COMPUTE(BUFB) do {                                                    \
        __builtin_amdgcn_s_setprio(1);                                        \
        _Pragma("unroll")                                                     \
        for (int t = 0; t < 9; ++t) {                                         \
            const int kh = t / 3, kw = t - kh * 3;                            \
            short8 bf[4];                                                     \
            _Pragma("unroll")                                                 \
            for (int j = 0; j < 4; ++j)                                       \
                bf[j] = *(const short8*)(smem + (BUFB) + ABUF +               \
                        (((t * 4 + q) * 64) + j * 16 + li) * 16);             \
            _Pragma("unroll")                                                 \
            for (int i = 0; i < 4; ++i) {                                     \
                short8 af = *(const short8*)(smem + (BUFB) +                  \
                        ((((wid + kh) * 4 + q) * 66) + (i * 16 + li + kw)) * 16); \
                _Pragma("unroll")                                             \
                for (int j = 0; j < 4; ++j)                                   \
                    acc[i][j] = __builtin_amdgcn_mfma_f32_16x16x32_bf16(      \
                        af, bf[j], acc[i][j], 0, 0, 0);                       \
            }                                                                 \
        }                                                                     \
        __builtin_amdgcn_s_setprio(0);                                        \
    } while (0)

#define SYNC() do {                                                           \
        asm volatile("s_waitcnt vmcnt(0)" ::: "memory");                      \
        __builtin_amdgcn_s_barrier();                                         \
    } while (0)

    // prologue: stage cc=0 into buf0
    STAGE(0, 0);
    SYNC();

#pragma unroll 1
    for (int cc = 0; cc < 16; cc += 2) {
        STAGE(cc + 1, BUFSZ);        // issue early: latency hides under taps
        COMPUTE(0);
        SYNC();                      // drain (cheap) + one barrier
        if (cc + 2 < 16) STAGE(cc + 2, 0);
        COMPUTE(BUFSZ);
        SYNC();
    }

#undef STAGE
#undef COMPUTE
#undef SYNC

    // ---- epilogue: *dcoef + noise + bias -> lrelu*gain ----
    const float ns = nstr[0];
    const int row = y0 + wid;
#pragma unroll
    for (int j = 0; j < 4; ++j) {
        int cout = n0 + j * 16 + li;
        float dc = dcoef[b * COUT + cout];
        float bs = bias[cout];
        float* op = out + ((size_t)(b * COUT + cout) * RES + row) * RES;
#pragma unroll
        for (int i = 0; i < 4; ++i) {
            int colb = i * 16 + q * 4;
            float4v nz = *(const float4v*)(noise + row * RES + colb);
            float4v a = acc[i][j];
            float4v r;
            r.x = a.x * dc + nz.x * ns + bs;
            r.y = a.y * dc + nz.y * ns + bs;
            r.z = a.z * dc + nz.z * ns + bs;
            r.w = a.w * dc + nz.w * ns + bs;
            r.x = (r.x > 0.f ? r.x : LRELU * r.x) * ACT_GAIN;
            r.y = (r.y > 0.f ? r.y : LRELU * r.y) * ACT_GAIN;
            r.z = (r.z > 0.f ? r.z : LRELU * r.z) * ACT_GAIN;
            r.w = (r.w > 0.f ? r.w : LRELU * r.w) * ACT_GAIN;
            *(float4v*)(op + colb) = r;
        }
    }
}

extern "C" void kernel_launch(void* const* d_in, const int* in_sizes, int n_in,
                              void* d_out, int out_size, void* d_ws, size_t ws_size,
                              hipStream_t stream) {
    (void)in_sizes; (void)n_in; (void)out_size; (void)ws_size;
    const float* x     = (const float*)d_in[0];
    const float* w     = (const float*)d_in[1];
    const float* aw    = (const float*)d_in[2];
    const float* ab    = (const float*)d_in[3];
    const float* wt    = (const float*)d_in[4];
    const float* bias  = (const float*)d_in[5];
    const float* noise = (const float*)d_in[6];
    const float* nstr  = (const float*)d_in[7];
    float* out = (float*)d_out;

    static bool init = false;
    if (!init) {
        hipFuncSetAttribute(reinterpret_cast<const void*>(conv_mfma),
                            hipFuncAttributeMaxDynamicSharedMemorySize, LDS_TOT);
        init = true;
    }

    char* ws = (char*)d_ws;
    float* styles = (float*)ws;                                   // 32 KB
    float* dcoef  = (float*)(ws + 32768);                         // 32 KB
    float* wsq    = (float*)(ws + 65536);                         // 1 MB
    __hip_bfloat16* wb  = (__hip_bfloat16*)(ws + 65536 + 1048576);          // 4.72 MB
    __hip_bfloat16* xs2 = (__hip_bfloat16*)(ws + 65536 + 1048576 + 4718592); // 71.4 MB

    styles2_kernel<<<dim3(NB, 8), dim3(256), 0, stream>>>(w, aw, ab, styles);
    prep_weights<<<dim3(1024), dim3(256), 0, stream>>>(wt, wsq, wb);
    dcoef2_kernel<<<dim3(NB, 8), dim3(256), 0, stream>>>(styles, wsq, dcoef);
    upmod2_kernel<<<dim3(HUP, 4, NB), dim3(256), 0, stream>>>(x, styles, xs2);
    conv_mfma<<<dim3(8, 8, NB), dim3(512), LDS_TOT, stream>>>(
        xs2, wb, dcoef, bias, noise, nstr, out);
}